// Round 1
// baseline (739.601 us; speedup 1.0000x reference)
//
#include <hip/hip_runtime.h>
#include <math.h>

#define NTOK 4096
#define DDIM 1024
#define IDIM 4096
#define NEXP 8
#define MAXPAD 9216   // 8192 assignments + 8*128 worst-case tile padding

typedef _Float16 f16x8 __attribute__((ext_vector_type(8)));
typedef _Float16 f16x4 __attribute__((ext_vector_type(4)));
typedef float    f32x4 __attribute__((ext_vector_type(4)));

// ---------------- async global->LDS, 16B per lane, lane-ordered LDS dest ----
__device__ __forceinline__ void glds16(const _Float16* g, _Float16* l) {
    __builtin_amdgcn_global_load_lds(
        (const __attribute__((address_space(1))) _Float16*)g,
        (__attribute__((address_space(3))) _Float16*)l, 16, 0, 0);
}

// ---------------- fp32 -> fp16 weight conversion ----------------------------
__global__ void cvt_kernel(const float* __restrict__ src, _Float16* __restrict__ dst, int n4) {
    int i = blockIdx.x * blockDim.x + threadIdx.x;
    if (i >= n4) return;
    float4 v = ((const float4*)src)[i];
    f16x4 o = { (_Float16)v.x, (_Float16)v.y, (_Float16)v.z, (_Float16)v.w };
    ((f16x4*)dst)[i] = o;
}

// ---------------- gating: logits, top-2, softmax, atomic append -------------
__global__ void gate_kernel(const float* __restrict__ x, const float* __restrict__ gw,
                            const float* __restrict__ gb,
                            int* __restrict__ cnt, int* __restrict__ tok,
                            float* __restrict__ wgt) {
    int wave = threadIdx.x >> 6;
    int lane = threadIdx.x & 63;
    int token = blockIdx.x * 4 + wave;
    const float* xr = x + (size_t)token * DDIM;
    float xv[16];
#pragma unroll
    for (int j = 0; j < 16; ++j) xv[j] = xr[lane + 64 * j];
    float lg[NEXP];
#pragma unroll
    for (int e = 0; e < NEXP; ++e) {
        const float* g = gw + e * DDIM;
        float s = 0.f;
#pragma unroll
        for (int j = 0; j < 16; ++j) s += xv[j] * g[lane + 64 * j];
#pragma unroll
        for (int o = 32; o > 0; o >>= 1) s += __shfl_xor(s, o, 64);
        lg[e] = s + gb[e];
    }
    if (lane == 0) {
        int i0 = 0; float v0 = lg[0];
        for (int e = 1; e < NEXP; ++e) if (lg[e] > v0) { v0 = lg[e]; i0 = e; }
        int i1 = -1; float v1 = -3.0e38f;
        for (int e = 0; e < NEXP; ++e) { if (e == i0) continue; if (lg[e] > v1) { v1 = lg[e]; i1 = e; } }
        float e1 = expf(v1 - v0);
        float den = 1.f + e1;
        float w0 = 1.f / den;
        float w1 = e1 / den;
        int p0 = atomicAdd(&cnt[i0], 1);
        tok[i0 * NTOK + p0] = token; wgt[i0 * NTOK + p0] = w0;
        int p1 = atomicAdd(&cnt[i1], 1);
        tok[i1 * NTOK + p1] = token; wgt[i1 * NTOK + p1] = w1;
    }
}

// ---------------- prefix scan of 128-padded expert counts -------------------
__global__ void scan_kernel(const int* __restrict__ cnt, int* __restrict__ off) {
    if (threadIdx.x == 0) {
        int acc = 0;
        for (int e = 0; e < NEXP; ++e) { off[e] = acc; acc += ((cnt[e] + 127) >> 7) << 7; }
        off[NEXP] = acc;
    }
}

// ---------------- gather tokens into compacted fp16 activation rows ---------
__global__ void gather_kernel(const float* __restrict__ x, const int* __restrict__ cnt,
                              const int* __restrict__ off, const int* __restrict__ tok,
                              _Float16* __restrict__ xg) {
    int row = blockIdx.x;
    if (row >= off[NEXP]) return;
    int e = 0;
    while (e < NEXP - 1 && row >= off[e + 1]) ++e;
    int r = row - off[e];
    int t = threadIdx.x;
    _Float16* dst = xg + (size_t)row * DDIM;
    if (r < cnt[e]) {
        int token = tok[e * NTOK + r];
        float4 v = ((const float4*)(x + (size_t)token * DDIM))[t];
        f16x4 o = { (_Float16)v.x, (_Float16)v.y, (_Float16)v.z, (_Float16)v.w };
        ((f16x4*)dst)[t] = o;
    } else {
        f16x4 z = {};
        ((f16x4*)dst)[t] = z;   // zero padding rows so edge tiles are benign
    }
}

// ---------------- grouped GEMM, m97-style 128x128 tile, BK=32 ---------------
// EPI==1: h = gelu(A@W1^T + b1), store fp16    EPI==2: out += w*(A@W2^T + b2)
template <int KDIM, int NDIM, int EPI>
__global__ __launch_bounds__(256, 2) void gemm_kernel(
    const _Float16* __restrict__ A,     // [MAXPAD][KDIM] compacted rows
    const _Float16* __restrict__ Bw,    // [E][NDIM][KDIM] (K-major / B^T form)
    const float* __restrict__ bias,     // [E][NDIM]
    const int* __restrict__ cnt, const int* __restrict__ off,
    const int* __restrict__ tok, const float* __restrict__ wgt,
    _Float16* __restrict__ Hout, float* __restrict__ Out) {
    int e = blockIdx.z;
    int ce = cnt[e];
    int mtiles = (ce + 127) >> 7;
    if ((int)blockIdx.y >= mtiles) return;
    int rowbase = off[e] + blockIdx.y * 128;
    int colbase = blockIdx.x * 128;

    __shared__ __align__(16) _Float16 As[128 * 32];
    __shared__ __align__(16) _Float16 Bs[128 * 32];

    int tid = threadIdx.x;
    int wv = tid >> 6, lane = tid & 63;
    int wm = (wv >> 1) * 64, wn = (wv & 1) * 64;

    const _Float16* Abase = A + (size_t)rowbase * KDIM;
    const _Float16* Bbase = Bw + (size_t)e * NDIM * KDIM + (size_t)colbase * KDIM;

    int ldrow = wv * 32 + (lane >> 2);     // staging row for this lane (inst0; inst1 = +16)
    int ldcol = (lane & 3) * 8;            // fp16 element offset within 64B row chunk

    int fr = lane & 15;                    // fragment row/col
    int fk = (lane >> 4) * 8;              // fragment k offset

    f32x4 acc[4][4] = {};

    for (int k0 = 0; k0 < KDIM; k0 += 32) {
        __syncthreads();
        glds16(Abase + (size_t)ldrow * KDIM + k0 + ldcol,        &As[(wv * 32) * 32]);
        glds16(Abase + (size_t)(ldrow + 16) * KDIM + k0 + ldcol, &As[(wv * 32 + 16) * 32]);
        glds16(Bbase + (size_t)ldrow * KDIM + k0 + ldcol,        &Bs[(wv * 32) * 32]);
        glds16(Bbase + (size_t)(ldrow + 16) * KDIM + k0 + ldcol, &Bs[(wv * 32 + 16) * 32]);
        __syncthreads();
        f16x8 a[4], b[4];
#pragma unroll
        for (int i = 0; i < 4; ++i) a[i] = *(const f16x8*)&As[(wm + i * 16 + fr) * 32 + fk];
#pragma unroll
        for (int j = 0; j < 4; ++j) b[j] = *(const f16x8*)&Bs[(wn + j * 16 + fr) * 32 + fk];
#pragma unroll
        for (int i = 0; i < 4; ++i)
#pragma unroll
            for (int j = 0; j < 4; ++j)
                acc[i][j] = __builtin_amdgcn_mfma_f32_16x16x32_f16(a[i], b[j], acc[i][j], 0, 0, 0);
    }

    int rquad = (lane >> 4) * 4;
#pragma unroll
    for (int i = 0; i < 4; ++i) {
#pragma unroll
        for (int j = 0; j < 4; ++j) {
#pragma unroll
            for (int r = 0; r < 4; ++r) {
                int ml = wm + i * 16 + rquad + r;       // C/D: row=(lane>>4)*4+reg
                int nl = wn + j * 16 + fr;              //      col=lane&15
                float v = acc[i][j][r];
                int col = colbase + nl;
                if (EPI == 1) {
                    v += bias[e * NDIM + col];
                    v = 0.5f * v * (1.0f + erff(v * 0.70710678118654752f));
                    Hout[(size_t)(rowbase + ml) * NDIM + col] = (_Float16)v;
                } else {
                    int slot = blockIdx.y * 128 + ml;
                    if (slot < ce) {
                        int token = tok[e * NTOK + slot];
                        float w = wgt[e * NTOK + slot];
                        unsafeAtomicAdd(&Out[(size_t)token * NDIM + col],
                                        w * (v + bias[e * NDIM + col]));
                    }
                }
            }
        }
    }
}

extern "C" void kernel_launch(void* const* d_in, const int* in_sizes, int n_in,
                              void* d_out, int out_size, void* d_ws, size_t ws_size,
                              hipStream_t stream) {
    const float* x      = (const float*)d_in[0];
    const float* gate_w = (const float*)d_in[1];
    const float* gate_b = (const float*)d_in[2];
    const float* w1     = (const float*)d_in[3];
    const float* b1     = (const float*)d_in[4];
    const float* w2     = (const float*)d_in[5];
    const float* b2     = (const float*)d_in[6];
    float* out = (float*)d_out;

    // workspace layout (~229 MB)
    char* p = (char*)d_ws;
    _Float16* w1h  = (_Float16*)p; p += (size_t)NEXP * IDIM * DDIM * 2;  // 64 MB
    _Float16* w2h  = (_Float16*)p; p += (size_t)NEXP * DDIM * IDIM * 2;  // 64 MB
    _Float16* xg   = (_Float16*)p; p += (size_t)MAXPAD * DDIM * 2;       // 18 MB
    _Float16* hbuf = (_Float16*)p; p += (size_t)MAXPAD * IDIM * 2;       // 72 MB
    int*      tok  = (int*)p;      p += (size_t)NEXP * NTOK * 4;
    float*    wgt  = (float*)p;    p += (size_t)NEXP * NTOK * 4;
    int*      cnt  = (int*)p;      p += 128;
    int*      off  = (int*)p;      p += 128;

    hipMemsetAsync(cnt, 0, 128, stream);
    hipMemsetAsync(out, 0, (size_t)NTOK * DDIM * 4, stream);

    cvt_kernel<<<32768, 256, 0, stream>>>(w1, w1h, NEXP * IDIM * DDIM / 4);
    cvt_kernel<<<32768, 256, 0, stream>>>(w2, w2h, NEXP * DDIM * IDIM / 4);
    gate_kernel<<<NTOK / 4, 256, 0, stream>>>(x, gate_w, gate_b, cnt, tok, wgt);
    scan_kernel<<<1, 64, 0, stream>>>(cnt, off);
    gather_kernel<<<MAXPAD, 256, 0, stream>>>(x, cnt, off, tok, xg);

    // GEMM1: [rows x 1024] @ w1[e]^T -> gelu -> h [rows x 4096]
    gemm_kernel<DDIM, IDIM, 1><<<dim3(IDIM / 128, 32, NEXP), 256, 0, stream>>>(
        xg, w1h, b1, cnt, off, tok, wgt, hbuf, (float*)nullptr);
    // GEMM2: [rows x 4096] @ w2[e]^T -> scaled scatter-add into out
    gemm_kernel<IDIM, DDIM, 2><<<dim3(DDIM / 128, 32, NEXP), 256, 0, stream>>>(
        hbuf, w2h, b2, cnt, off, tok, wgt, (_Float16*)nullptr, out);
}

// Round 2
// 701.628 us; speedup vs baseline: 1.0541x; 1.0541x over previous
//
#include <hip/hip_runtime.h>
#include <math.h>

#define NTOK 4096
#define DDIM 1024
#define IDIM 4096
#define NEXP 8
#define MAXPAD 9216   // 8192 assignments + 8*128 worst-case tile padding

typedef _Float16 f16x8 __attribute__((ext_vector_type(8)));
typedef _Float16 f16x4 __attribute__((ext_vector_type(4)));
typedef float    f32x4 __attribute__((ext_vector_type(4)));

// ---------------- async global->LDS, 16B per lane, lane-ordered LDS dest ----
__device__ __forceinline__ void glds16(const _Float16* g, _Float16* l) {
    __builtin_amdgcn_global_load_lds(
        (const __attribute__((address_space(1))) _Float16*)g,
        (__attribute__((address_space(3))) _Float16*)l, 16, 0, 0);
}

// tanh-approx GELU: |err| vs exact erf-GELU <= ~3e-3, far under our margin.
// ~9 VALU ops (v_exp_f32 + v_rcp_f32) vs libm erff's branchy 20-30.
__device__ __forceinline__ float fast_gelu(float v) {
    float u = v * (0.7978845608f + 0.0356774081f * v * v);
    float ex = __builtin_amdgcn_exp2f(u * 2.8853900817779268f);  // exp(2u)
    float th = 1.0f - 2.0f * __builtin_amdgcn_rcpf(ex + 1.0f);   // tanh(u)
    return 0.5f * v * (1.0f + th);
}

// ---------------- fp32 -> fp16 weight conversion ----------------------------
__global__ void cvt_kernel(const float* __restrict__ src, _Float16* __restrict__ dst, int n4) {
    int i = blockIdx.x * blockDim.x + threadIdx.x;
    if (i >= n4) return;
    float4 v = ((const float4*)src)[i];
    f16x4 o = { (_Float16)v.x, (_Float16)v.y, (_Float16)v.z, (_Float16)v.w };
    ((f16x4*)dst)[i] = o;
}

// ---------------- gating: logits, top-2, softmax, atomic append -------------
__global__ void gate_kernel(const float* __restrict__ x, const float* __restrict__ gw,
                            const float* __restrict__ gb,
                            int* __restrict__ cnt, int* __restrict__ tok,
                            float* __restrict__ wgt) {
    int wave = threadIdx.x >> 6;
    int lane = threadIdx.x & 63;
    int token = blockIdx.x * 4 + wave;
    const float* xr = x + (size_t)token * DDIM;
    float xv[16];
#pragma unroll
    for (int j = 0; j < 16; ++j) xv[j] = xr[lane + 64 * j];
    float lg[NEXP];
#pragma unroll
    for (int e = 0; e < NEXP; ++e) {
        const float* g = gw + e * DDIM;
        float s = 0.f;
#pragma unroll
        for (int j = 0; j < 16; ++j) s += xv[j] * g[lane + 64 * j];
#pragma unroll
        for (int o = 32; o > 0; o >>= 1) s += __shfl_xor(s, o, 64);
        lg[e] = s + gb[e];
    }
    if (lane == 0) {
        int i0 = 0; float v0 = lg[0];
        for (int e = 1; e < NEXP; ++e) if (lg[e] > v0) { v0 = lg[e]; i0 = e; }
        int i1 = -1; float v1 = -3.0e38f;
        for (int e = 0; e < NEXP; ++e) { if (e == i0) continue; if (lg[e] > v1) { v1 = lg[e]; i1 = e; } }
        float e1 = expf(v1 - v0);
        float den = 1.f + e1;
        float w0 = 1.f / den;
        float w1 = e1 / den;
        int p0 = atomicAdd(&cnt[i0], 1);
        tok[i0 * NTOK + p0] = token; wgt[i0 * NTOK + p0] = w0;
        int p1 = atomicAdd(&cnt[i1], 1);
        tok[i1 * NTOK + p1] = token; wgt[i1 * NTOK + p1] = w1;
    }
}

// ---------------- prefix scan of 128-padded expert counts -------------------
__global__ void scan_kernel(const int* __restrict__ cnt, int* __restrict__ off) {
    if (threadIdx.x == 0) {
        int acc = 0;
        for (int e = 0; e < NEXP; ++e) { off[e] = acc; acc += ((cnt[e] + 127) >> 7) << 7; }
        off[NEXP] = acc;
    }
}

// ---------------- gather tokens into compacted fp16 activation rows ---------
__global__ void gather_kernel(const float* __restrict__ x, const int* __restrict__ cnt,
                              const int* __restrict__ off, const int* __restrict__ tok,
                              _Float16* __restrict__ xg) {
    int row = blockIdx.x;
    if (row >= off[NEXP]) return;
    int e = 0;
    while (e < NEXP - 1 && row >= off[e + 1]) ++e;
    int r = row - off[e];
    int t = threadIdx.x;
    _Float16* dst = xg + (size_t)row * DDIM;
    if (r < cnt[e]) {
        int token = tok[e * NTOK + r];
        float4 v = ((const float4*)(x + (size_t)token * DDIM))[t];
        f16x4 o = { (_Float16)v.x, (_Float16)v.y, (_Float16)v.z, (_Float16)v.w };
        ((f16x4*)dst)[t] = o;
    } else {
        f16x4 z = {};
        ((f16x4*)dst)[t] = z;   // zero padding rows so edge tiles are benign
    }
}

// ---------------- grouped GEMM, m97-style 128x128 tile, BK=32, split-K ------
// EPI==1: h = gelu(A@W1^T + b1), store fp16    EPI==2: out += w*(A@W2^T + b2)
// SPLIT: K split into SPLIT chunks, one block per chunk (EPI==2 atomics make
//        split-K free; bias contributed by chunk 0 only).
template <int KDIM, int NDIM, int EPI, int SPLIT>
__global__ __launch_bounds__(256, 2) void gemm_kernel(
    const _Float16* __restrict__ A,     // [MAXPAD][KDIM] compacted rows
    const _Float16* __restrict__ Bw,    // [E][NDIM][KDIM] (K-major / B^T form)
    const float* __restrict__ bias,     // [E][NDIM]
    const int* __restrict__ cnt, const int* __restrict__ off,
    const int* __restrict__ tok, const float* __restrict__ wgt,
    _Float16* __restrict__ Hout, float* __restrict__ Out) {
    int e  = blockIdx.z / SPLIT;
    int kc = blockIdx.z % SPLIT;
    const int KB = KDIM / SPLIT;        // K elements this block accumulates
    int ce = cnt[e];
    int mtiles = (ce + 127) >> 7;
    if ((int)blockIdx.y >= mtiles) return;
    int rowbase = off[e] + blockIdx.y * 128;
    int colbase = blockIdx.x * 128;

    __shared__ __align__(16) _Float16 As[128 * 32];
    __shared__ __align__(16) _Float16 Bs[128 * 32];

    int tid = threadIdx.x;
    int wv = tid >> 6, lane = tid & 63;
    int wm = (wv >> 1) * 64, wn = (wv & 1) * 64;

    const _Float16* Abase = A + (size_t)rowbase * KDIM + kc * KB;
    const _Float16* Bbase = Bw + (size_t)e * NDIM * KDIM + (size_t)colbase * KDIM + kc * KB;

    int ldrow = wv * 32 + (lane >> 2);     // staging row for this lane (inst0; inst1 = +16)
    int ldcol = (lane & 3) * 8;            // fp16 element offset within 64B row chunk

    int fr = lane & 15;                    // fragment row/col
    int fk = (lane >> 4) * 8;              // fragment k offset

    f32x4 acc[4][4] = {};

    for (int k0 = 0; k0 < KB; k0 += 32) {
        __syncthreads();
        glds16(Abase + (size_t)ldrow * KDIM + k0 + ldcol,        &As[(wv * 32) * 32]);
        glds16(Abase + (size_t)(ldrow + 16) * KDIM + k0 + ldcol, &As[(wv * 32 + 16) * 32]);
        glds16(Bbase + (size_t)ldrow * KDIM + k0 + ldcol,        &Bs[(wv * 32) * 32]);
        glds16(Bbase + (size_t)(ldrow + 16) * KDIM + k0 + ldcol, &Bs[(wv * 32 + 16) * 32]);
        __syncthreads();
        f16x8 a[4], b[4];
#pragma unroll
        for (int i = 0; i < 4; ++i) a[i] = *(const f16x8*)&As[(wm + i * 16 + fr) * 32 + fk];
#pragma unroll
        for (int j = 0; j < 4; ++j) b[j] = *(const f16x8*)&Bs[(wn + j * 16 + fr) * 32 + fk];
#pragma unroll
        for (int i = 0; i < 4; ++i)
#pragma unroll
            for (int j = 0; j < 4; ++j)
                acc[i][j] = __builtin_amdgcn_mfma_f32_16x16x32_f16(a[i], b[j], acc[i][j], 0, 0, 0);
    }

    int rquad = (lane >> 4) * 4;
    if (EPI == 1) {
#pragma unroll
        for (int i = 0; i < 4; ++i) {
#pragma unroll
            for (int j = 0; j < 4; ++j) {
                int col = colbase + wn + j * 16 + fr;
                float bb = bias[e * NDIM + col];
#pragma unroll
                for (int r = 0; r < 4; ++r) {
                    int ml = wm + i * 16 + rquad + r;   // C/D: row=(lane>>4)*4+reg
                    float v = fast_gelu(acc[i][j][r] + bb);
                    Hout[(size_t)(rowbase + ml) * NDIM + col] = (_Float16)v;
                }
            }
        }
    } else {
#pragma unroll
        for (int i = 0; i < 4; ++i) {
#pragma unroll
            for (int r = 0; r < 4; ++r) {
                int ml = wm + i * 16 + rquad + r;
                int slot = blockIdx.y * 128 + ml;
                if (slot < ce) {
                    int token = tok[e * NTOK + slot];
                    float w = wgt[e * NTOK + slot];
#pragma unroll
                    for (int j = 0; j < 4; ++j) {
                        int col = colbase + wn + j * 16 + fr;
                        float v = acc[i][j][r];
                        if (kc == 0) v += bias[e * NDIM + col];  // bias once per split-K group
                        unsafeAtomicAdd(&Out[(size_t)token * NDIM + col], w * v);
                    }
                }
            }
        }
    }
}

extern "C" void kernel_launch(void* const* d_in, const int* in_sizes, int n_in,
                              void* d_out, int out_size, void* d_ws, size_t ws_size,
                              hipStream_t stream) {
    const float* x      = (const float*)d_in[0];
    const float* gate_w = (const float*)d_in[1];
    const float* gate_b = (const float*)d_in[2];
    const float* w1     = (const float*)d_in[3];
    const float* b1     = (const float*)d_in[4];
    const float* w2     = (const float*)d_in[5];
    const float* b2     = (const float*)d_in[6];
    float* out = (float*)d_out;

    // workspace layout (~229 MB)
    char* p = (char*)d_ws;
    _Float16* w1h  = (_Float16*)p; p += (size_t)NEXP * IDIM * DDIM * 2;  // 64 MB
    _Float16* w2h  = (_Float16*)p; p += (size_t)NEXP * DDIM * IDIM * 2;  // 64 MB
    _Float16* xg   = (_Float16*)p; p += (size_t)MAXPAD * DDIM * 2;       // 18 MB
    _Float16* hbuf = (_Float16*)p; p += (size_t)MAXPAD * IDIM * 2;       // 72 MB
    int*      tok  = (int*)p;      p += (size_t)NEXP * NTOK * 4;
    float*    wgt  = (float*)p;    p += (size_t)NEXP * NTOK * 4;
    int*      cnt  = (int*)p;      p += 128;
    int*      off  = (int*)p;      p += 128;

    hipMemsetAsync(cnt, 0, 128, stream);
    hipMemsetAsync(out, 0, (size_t)NTOK * DDIM * 4, stream);

    cvt_kernel<<<32768, 256, 0, stream>>>(w1, w1h, NEXP * IDIM * DDIM / 4);
    cvt_kernel<<<32768, 256, 0, stream>>>(w2, w2h, NEXP * DDIM * IDIM / 4);
    gate_kernel<<<NTOK / 4, 256, 0, stream>>>(x, gate_w, gate_b, cnt, tok, wgt);
    scan_kernel<<<1, 64, 0, stream>>>(cnt, off);
    gather_kernel<<<MAXPAD, 256, 0, stream>>>(x, cnt, off, tok, xg);

    // GEMM1: [rows x 1024] @ w1[e]^T -> gelu -> h [rows x 4096]
    gemm_kernel<DDIM, IDIM, 1, 1><<<dim3(IDIM / 128, 32, NEXP), 256, 0, stream>>>(
        xg, w1h, b1, cnt, off, tok, wgt, hbuf, (float*)nullptr);
    // GEMM2: [rows x 4096] @ w2[e]^T -> scaled scatter-add into out, split-K x4
    gemm_kernel<IDIM, DDIM, 2, 4><<<dim3(DDIM / 128, 32, NEXP * 4), 256, 0, stream>>>(
        hbuf, w2h, b2, cnt, off, tok, wgt, (_Float16*)nullptr, out);
}

// Round 3
// 701.004 us; speedup vs baseline: 1.0551x; 1.0009x over previous
//
#include <hip/hip_runtime.h>
#include <math.h>

#define NTOK 4096
#define DDIM 1024
#define IDIM 4096
#define NEXP 8
#define MAXPAD 9216   // 8192 assignments + 8*128 worst-case tile padding

typedef _Float16 f16x8 __attribute__((ext_vector_type(8)));
typedef _Float16 f16x4 __attribute__((ext_vector_type(4)));
typedef float    f32x4 __attribute__((ext_vector_type(4)));

// ---------------- async global->LDS, 16B per lane, lane-ordered LDS dest ----
__device__ __forceinline__ void glds16(const _Float16* g, _Float16* l) {
    __builtin_amdgcn_global_load_lds(
        (const __attribute__((address_space(1))) _Float16*)g,
        (__attribute__((address_space(3))) _Float16*)l, 16, 0, 0);
}

// tanh-approx GELU: |err| vs exact erf-GELU <= ~3e-3, far under our margin.
__device__ __forceinline__ float fast_gelu(float v) {
    float u = v * (0.7978845608f + 0.0356774081f * v * v);
    float ex = __builtin_amdgcn_exp2f(u * 2.8853900817779268f);  // exp(2u)
    float th = 1.0f - 2.0f * __builtin_amdgcn_rcpf(ex + 1.0f);   // tanh(u)
    return 0.5f * v * (1.0f + th);
}

// ---------------- fp32 -> fp16 weight conversion ----------------------------
__global__ void cvt_kernel(const float* __restrict__ src, _Float16* __restrict__ dst, int n4) {
    int i = blockIdx.x * blockDim.x + threadIdx.x;
    if (i >= n4) return;
    float4 v = ((const float4*)src)[i];
    f16x4 o = { (_Float16)v.x, (_Float16)v.y, (_Float16)v.z, (_Float16)v.w };
    ((f16x4*)dst)[i] = o;
}

// ---------------- gating: logits, top-2, softmax, atomic append -------------
__global__ void gate_kernel(const float* __restrict__ x, const float* __restrict__ gw,
                            const float* __restrict__ gb,
                            int* __restrict__ cnt, int* __restrict__ tok,
                            float* __restrict__ wgt) {
    int wave = threadIdx.x >> 6;
    int lane = threadIdx.x & 63;
    int token = blockIdx.x * 4 + wave;
    const float* xr = x + (size_t)token * DDIM;
    float xv[16];
#pragma unroll
    for (int j = 0; j < 16; ++j) xv[j] = xr[lane + 64 * j];
    float lg[NEXP];
#pragma unroll
    for (int e = 0; e < NEXP; ++e) {
        const float* g = gw + e * DDIM;
        float s = 0.f;
#pragma unroll
        for (int j = 0; j < 16; ++j) s += xv[j] * g[lane + 64 * j];
#pragma unroll
        for (int o = 32; o > 0; o >>= 1) s += __shfl_xor(s, o, 64);
        lg[e] = s + gb[e];
    }
    if (lane == 0) {
        int i0 = 0; float v0 = lg[0];
        for (int e = 1; e < NEXP; ++e) if (lg[e] > v0) { v0 = lg[e]; i0 = e; }
        int i1 = -1; float v1 = -3.0e38f;
        for (int e = 0; e < NEXP; ++e) { if (e == i0) continue; if (lg[e] > v1) { v1 = lg[e]; i1 = e; } }
        float e1 = expf(v1 - v0);
        float den = 1.f + e1;
        float w0 = 1.f / den;
        float w1 = e1 / den;
        int p0 = atomicAdd(&cnt[i0], 1);
        tok[i0 * NTOK + p0] = token; wgt[i0 * NTOK + p0] = w0;
        int p1 = atomicAdd(&cnt[i1], 1);
        tok[i1 * NTOK + p1] = token; wgt[i1 * NTOK + p1] = w1;
    }
}

// ---------------- prefix scan of 128-padded expert counts -------------------
__global__ void scan_kernel(const int* __restrict__ cnt, int* __restrict__ off) {
    if (threadIdx.x == 0) {
        int acc = 0;
        for (int e = 0; e < NEXP; ++e) { off[e] = acc; acc += ((cnt[e] + 127) >> 7) << 7; }
        off[NEXP] = acc;
    }
}

// ---------------- gather tokens into compacted fp16 activation rows ---------
__global__ void gather_kernel(const float* __restrict__ x, const int* __restrict__ cnt,
                              const int* __restrict__ off, const int* __restrict__ tok,
                              _Float16* __restrict__ xg) {
    int row = blockIdx.x;
    if (row >= off[NEXP]) return;
    int e = 0;
    while (e < NEXP - 1 && row >= off[e + 1]) ++e;
    int r = row - off[e];
    int t = threadIdx.x;
    _Float16* dst = xg + (size_t)row * DDIM;
    if (r < cnt[e]) {
        int token = tok[e * NTOK + r];
        float4 v = ((const float4*)(x + (size_t)token * DDIM))[t];
        f16x4 o = { (_Float16)v.x, (_Float16)v.y, (_Float16)v.z, (_Float16)v.w };
        ((f16x4*)dst)[t] = o;
    } else {
        f16x4 z = {};
        ((f16x4*)dst)[t] = z;   // zero padding rows so edge tiles are benign
    }
}

// ---------------- grouped GEMM, m97-style 128x128 tile, BK=32, split-K ------
// Grid: x = mt*NT + nt (so same-nt blocks share x%8 -> same XCD -> B-tile L2
// reuse, round-robin dispatch heuristic), z = e*SPLIT + kc.
// EPI==1: h = gelu(A@W1^T + b1), store fp16    EPI==2: out += w*(A@W2^T + b2)
template <int KDIM, int NDIM, int NT, int EPI, int SPLIT>
__global__ __launch_bounds__(256, 4) void gemm_kernel(
    const _Float16* __restrict__ A,     // [MAXPAD][KDIM] compacted rows
    const _Float16* __restrict__ Bw,    // [E][NDIM][KDIM] (K-major / B^T form)
    const float* __restrict__ bias,     // [E][NDIM]
    const int* __restrict__ cnt, const int* __restrict__ off,
    const int* __restrict__ tok, const float* __restrict__ wgt,
    _Float16* __restrict__ Hout, float* __restrict__ Out) {
    int e  = blockIdx.z / SPLIT;
    int kc = blockIdx.z % SPLIT;
    const int KB = KDIM / SPLIT;        // K elements this block accumulates
    int nt = blockIdx.x % NT;
    int mt = blockIdx.x / NT;
    int ce = cnt[e];
    int mtiles = (ce + 127) >> 7;
    if (mt >= mtiles) return;
    int rowbase = off[e] + mt * 128;
    int colbase = nt * 128;

    __shared__ __align__(16) _Float16 As[128 * 32];
    __shared__ __align__(16) _Float16 Bs[128 * 32];

    int tid = threadIdx.x;
    int wv = tid >> 6, lane = tid & 63;
    int wm = (wv >> 1) * 64, wn = (wv & 1) * 64;

    const _Float16* Abase = A + (size_t)rowbase * KDIM + kc * KB;
    const _Float16* Bbase = Bw + (size_t)e * NDIM * KDIM + (size_t)colbase * KDIM + kc * KB;

    int ldrow = wv * 32 + (lane >> 2);     // staging row for this lane (inst0; inst1 = +16)
    int ldcol = (lane & 3) * 8;            // fp16 element offset within 64B row chunk

    int fr = lane & 15;                    // fragment row/col
    int fk = (lane >> 4) * 8;              // fragment k offset

    f32x4 acc[4][4] = {};

    for (int k0 = 0; k0 < KB; k0 += 32) {
        __syncthreads();
        glds16(Abase + (size_t)ldrow * KDIM + k0 + ldcol,        &As[(wv * 32) * 32]);
        glds16(Abase + (size_t)(ldrow + 16) * KDIM + k0 + ldcol, &As[(wv * 32 + 16) * 32]);
        glds16(Bbase + (size_t)ldrow * KDIM + k0 + ldcol,        &Bs[(wv * 32) * 32]);
        glds16(Bbase + (size_t)(ldrow + 16) * KDIM + k0 + ldcol, &Bs[(wv * 32 + 16) * 32]);
        __syncthreads();
        f16x8 a[4], b[4];
#pragma unroll
        for (int i = 0; i < 4; ++i) a[i] = *(const f16x8*)&As[(wm + i * 16 + fr) * 32 + fk];
#pragma unroll
        for (int j = 0; j < 4; ++j) b[j] = *(const f16x8*)&Bs[(wn + j * 16 + fr) * 32 + fk];
#pragma unroll
        for (int i = 0; i < 4; ++i)
#pragma unroll
            for (int j = 0; j < 4; ++j)
                acc[i][j] = __builtin_amdgcn_mfma_f32_16x16x32_f16(a[i], b[j], acc[i][j], 0, 0, 0);
    }

    int rquad = (lane >> 4) * 4;
    if (EPI == 1) {
#pragma unroll
        for (int i = 0; i < 4; ++i) {
#pragma unroll
            for (int j = 0; j < 4; ++j) {
                int col = colbase + wn + j * 16 + fr;
                float bb = bias[e * NDIM + col];
#pragma unroll
                for (int r = 0; r < 4; ++r) {
                    int ml = wm + i * 16 + rquad + r;   // C/D: row=(lane>>4)*4+reg
                    float v = fast_gelu(acc[i][j][r] + bb);
                    Hout[(size_t)(rowbase + ml) * NDIM + col] = (_Float16)v;
                }
            }
        }
    } else {
#pragma unroll
        for (int i = 0; i < 4; ++i) {
#pragma unroll
            for (int r = 0; r < 4; ++r) {
                int ml = wm + i * 16 + rquad + r;
                int slot = mt * 128 + ml;
                if (slot < ce) {
                    int token = tok[e * NTOK + slot];
                    float w = wgt[e * NTOK + slot];
#pragma unroll
                    for (int j = 0; j < 4; ++j) {
                        int col = colbase + wn + j * 16 + fr;
                        float v = acc[i][j][r];
                        if (kc == 0) v += bias[e * NDIM + col];  // bias once per split-K group
                        unsafeAtomicAdd(&Out[(size_t)token * NDIM + col], w * v);
                    }
                }
            }
        }
    }
}

extern "C" void kernel_launch(void* const* d_in, const int* in_sizes, int n_in,
                              void* d_out, int out_size, void* d_ws, size_t ws_size,
                              hipStream_t stream) {
    const float* x      = (const float*)d_in[0];
    const float* gate_w = (const float*)d_in[1];
    const float* gate_b = (const float*)d_in[2];
    const float* w1     = (const float*)d_in[3];
    const float* b1     = (const float*)d_in[4];
    const float* w2     = (const float*)d_in[5];
    const float* b2     = (const float*)d_in[6];
    float* out = (float*)d_out;

    // workspace layout (~229 MB)
    char* p = (char*)d_ws;
    _Float16* w1h  = (_Float16*)p; p += (size_t)NEXP * IDIM * DDIM * 2;  // 64 MB
    _Float16* w2h  = (_Float16*)p; p += (size_t)NEXP * DDIM * IDIM * 2;  // 64 MB
    _Float16* xg   = (_Float16*)p; p += (size_t)MAXPAD * DDIM * 2;       // 18 MB
    _Float16* hbuf = (_Float16*)p; p += (size_t)MAXPAD * IDIM * 2;       // 72 MB
    int*      tok  = (int*)p;      p += (size_t)NEXP * NTOK * 4;
    float*    wgt  = (float*)p;    p += (size_t)NEXP * NTOK * 4;
    int*      cnt  = (int*)p;      p += 128;
    int*      off  = (int*)p;      p += 128;

    hipMemsetAsync(cnt, 0, 128, stream);
    hipMemsetAsync(out, 0, (size_t)NTOK * DDIM * 4, stream);

    cvt_kernel<<<32768, 256, 0, stream>>>(w1, w1h, NEXP * IDIM * DDIM / 4);
    cvt_kernel<<<32768, 256, 0, stream>>>(w2, w2h, NEXP * DDIM * IDIM / 4);
    gate_kernel<<<NTOK / 4, 256, 0, stream>>>(x, gate_w, gate_b, cnt, tok, wgt);
    scan_kernel<<<1, 64, 0, stream>>>(cnt, off);
    gather_kernel<<<MAXPAD, 256, 0, stream>>>(x, cnt, off, tok, xg);

    // GEMM1: [rows x 1024] @ w1[e]^T -> gelu -> h [rows x 4096]
    // grid.x = 32 mtiles * 32 ntiles (flattened, nt fastest for XCD affinity)
    gemm_kernel<DDIM, IDIM, IDIM / 128, 1, 1><<<dim3(32 * (IDIM / 128), 1, NEXP), 256, 0, stream>>>(
        xg, w1h, b1, cnt, off, tok, wgt, hbuf, (float*)nullptr);
    // GEMM2: [rows x 4096] @ w2[e]^T -> scaled scatter-add into out, split-K x4
    gemm_kernel<IDIM, DDIM, DDIM / 128, 2, 4><<<dim3(32 * (DDIM / 128), 1, NEXP * 4), 256, 0, stream>>>(
        hbuf, w2h, b2, cnt, off, tok, wgt, (_Float16*)nullptr, out);
}